// Round 12
// baseline (296.583 us; speedup 1.0000x reference)
//
#include <hip/hip_runtime.h>
#include <hip/hip_bf16.h>
#include <stdint.h>

// NeuralFSM as integer FSM (exact). R12: collapse the build pipeline.
//  - R11: mega 128.7us (floor-ish), build ~156us across 6 dispatches for only
//    ~150MB traffic -> drain/gap/ramp-bound, not work-bound.
//  - build_kernel: ONE persistent 500x512 kernel = count (per-wave LDS hists)
//    -> grid barrier -> block0 scans 250 bucket totals -> grid barrier ->
//    reservation (atomicAdd per-bucket relative cursor) + LDS-staged scatter
//    + coalesced csr write. No per-chunk hist array, no p2a/p2b kernels.
//    Cross-block scalars via coherence-point atomics + sc1 loads (proven).
//  - p4 folded into mega prologue: block b bin-sorts its OWN bucket's two
//    halves by src>>8 (all csr traffic block-local; one less dispatch).
//  - mega iterations unchanged from R9/R11 (coherent x4 reload, fence-free
//    2-level barrier).
//  - Dispatches: memsetAsync(bar) + decode + build + mega.

#define NN 100000
#define EE 6400000
#define NCHARS 2048
#define ITERS 20

#define NBKT 250          // dst buckets == mega blocks
#define NPB 400           // nodes per bucket
#define WPS 12500         // words of packed state (NN/8)
#define X4N 3125          // WPS/4
#define CEDGE 12800       // edges per chunk (== build block)
#define NCHUNK 500        // build blocks
#define HCAP 13312        // mega-prologue half-bucket LDS cap (words)

// ---- bar region (words; lines 64B apart); zeroed by hipMemsetAsync ----
#define BLD_ARR(i)  ((i) * 16)          // 50 lines, 10 blocks each
#define BLD_TOP     800
#define BLD_REL(i)  (832 + (i) * 16)
#define MEG_ARR(i)  (1664 + (i) * 16)   // 25 lines, 10 blocks each
#define MEG_TOP     2080
#define MEG_REL(i)  (2112 + (i) * 16)
#define CNT_OFF     3072                // counts[250]
#define CUR_OFF     3328                // cursorRel[250]
#define BAR_WORDS   4096                // 16 KB

typedef uint32_t u32x4 __attribute__((ext_vector_type(4)));

__device__ inline uint32_t load_dw_sc1(const uint32_t* p) {
    uint32_t v;
    asm volatile("global_load_dword %0, %1, off sc1\n\ts_waitcnt vmcnt(0)"
                 : "=v"(v) : "v"(p) : "memory");
    return v;
}

__device__ inline void grid_barrier(uint32_t* bar, int line, uint32_t epoch,
                                    uint32_t perline, uint32_t nlines,
                                    int arrBase, int topOff, int relBase) {
    __syncthreads();                      // drains vmcnt: prior ops at coherence pt
    if (threadIdx.x == 0) {
        uint32_t old = atomicAdd(&bar[arrBase + line * 16], 1u);
        if (old + 1u == perline * epoch) {
            uint32_t told = atomicAdd(&bar[topOff], 1u);
            if (told + 1u == nlines * epoch) {
                for (uint32_t r = 0; r < nlines; ++r)
                    atomicExch(&bar[relBase + r * 16], epoch);
            }
        }
        while (__hip_atomic_load(&bar[relBase + line * 16], __ATOMIC_RELAXED,
                                 __HIP_MEMORY_SCOPE_AGENT) < epoch)
            __builtin_amdgcn_s_sleep(16);
    }
    __syncthreads();
}

// ---------- decode: nextT table + packed state ----------
__global__ void decode_kernel(const float* __restrict__ s0,
                              const float* __restrict__ T,
                              uint32_t* __restrict__ gPk0,
                              uint8_t* __restrict__ nextT) {
    int i = blockIdx.x * blockDim.x + threadIdx.x;
    int stride = gridDim.x * blockDim.x;
    if (i < NCHARS) {
        const float* row = T + i * 8;
        int t = 0;
        #pragma unroll
        for (int k = 1; k < 8; ++k) if (row[k] > 0.5f) t = k;
        nextT[i] = (uint8_t)t;
    }
    for (int j = i; j < WPS; j += stride) {
        uint32_t wv = 0;
        const float* rows = s0 + (size_t)j * 64;          // 8 nodes x 8 states
        #pragma unroll
        for (int k = 0; k < 8; ++k) {
            const float* row = rows + k * 8;
            int s = 0;
            #pragma unroll
            for (int q = 1; q < 8; ++q) if (row[q] > 0.5f) s = q;
            wv |= (uint32_t)s << (k << 2);
        }
        gPk0[j] = wv;
    }
}

// ---------- build: count -> [bar] -> scan -> [bar] -> reserve+scatter ----------
__global__ void __launch_bounds__(512) build_kernel(const int* __restrict__ src,
                                                    const int* __restrict__ dst,
                                                    uint32_t* __restrict__ bucket_base,
                                                    uint32_t* __restrict__ csr,
                                                    uint32_t* __restrict__ bar) {
    __shared__ uint32_t stage[CEDGE];       // 51.2 KB
    __shared__ uint32_t cw[8][256];         // 8 KB: per-wave counts -> cursors
    __shared__ uint32_t scanb[512];
    __shared__ uint32_t loc[NBKT + 1];
    __shared__ uint32_t segoff[NBKT];
    int t = threadIdx.x, w = t >> 6;
    int c = blockIdx.x;
    int e0 = c * CEDGE;
    const int4* ps4 = (const int4*)(src + e0);
    const int4* pd4 = (const int4*)(dst + e0);
    uint32_t* countsG = bar + CNT_OFF;
    uint32_t* cursorG = bar + CUR_OFF;
    const int line = c % 50;

    // --- A: count (int4 groups; edge group 4i..4i+3 -> wave (i%512)>>6) ---
    for (int i = t; i < 8 * 256; i += 512) ((uint32_t*)cw)[i] = 0;
    __syncthreads();
    for (int i = t; i < CEDGE / 4; i += 512) {
        int4 d = pd4[i];
        atomicAdd(&cw[w][d.x / NPB], 1u);
        atomicAdd(&cw[w][d.y / NPB], 1u);
        atomicAdd(&cw[w][d.z / NPB], 1u);
        atomicAdd(&cw[w][d.w / NPB], 1u);
    }
    __syncthreads();
    uint32_t tot = 0;
    if (t < NBKT) {
        #pragma unroll
        for (int w2 = 0; w2 < 8; ++w2) tot += cw[w2][t];
        atomicAdd(&countsG[t], tot);              // global bucket totals
    }
    // local exclusive scan of tot -> loc (independent of global)
    scanb[t] = tot;
    __syncthreads();
    for (int off = 1; off < 512; off <<= 1) {
        uint32_t x = (t >= off) ? scanb[t - off] : 0u;
        __syncthreads();
        scanb[t] += x;
        __syncthreads();
    }
    if (t < NBKT) loc[t] = scanb[t] - tot;
    if (t == 0) loc[NBKT] = CEDGE;

    grid_barrier(bar, line, 1u, 10u, 50u, 0, BLD_TOP, 832);

    // --- scan: block 0 only (block-uniform branch; __syncthreads safe) ---
    if (c == 0) {
        uint32_t v = 0;
        if (t < NBKT) v = load_dw_sc1(&countsG[t]);
        scanb[t] = v;
        __syncthreads();
        for (int off = 1; off < 512; off <<= 1) {
            uint32_t x = (t >= off) ? scanb[t - off] : 0u;
            __syncthreads();
            scanb[t] += x;
            __syncthreads();
        }
        if (t < NBKT)
            __hip_atomic_store(&bucket_base[t], scanb[t] - v,
                               __ATOMIC_RELAXED, __HIP_MEMORY_SCOPE_AGENT);
        if (t == 0)
            __hip_atomic_store(&bucket_base[NBKT], (uint32_t)EE,
                               __ATOMIC_RELAXED, __HIP_MEMORY_SCOPE_AGENT);
    }

    grid_barrier(bar, line, 2u, 10u, 50u, 0, BLD_TOP, 832);

    // --- C: reserve slice + per-wave cursors ---
    if (t < NBKT) {
        uint32_t bb_ = load_dw_sc1(&bucket_base[t]);
        uint32_t myStart = bb_ + atomicAdd(&cursorG[t], tot);
        segoff[t] = myStart - loc[t];
        uint32_t acc = loc[t];
        #pragma unroll
        for (int w2 = 0; w2 < 8; ++w2) {
            uint32_t cv = cw[w2][t];
            cw[w2][t] = acc;
            acc += cv;
        }
    }
    __syncthreads();
    // scatter (IDENTICAL int4-group wave mapping as count phase)
    for (int i = t; i < CEDGE / 4; i += 512) {
        int4 d = pd4[i];
        int4 s = ps4[i];
        int bb; uint32_t dl, pos;
        bb = d.x / NPB; dl = (uint32_t)(d.x - bb * NPB);
        pos = atomicAdd(&cw[w][bb], 1u); stage[pos] = ((uint32_t)s.x << 9) | dl;
        bb = d.y / NPB; dl = (uint32_t)(d.y - bb * NPB);
        pos = atomicAdd(&cw[w][bb], 1u); stage[pos] = ((uint32_t)s.y << 9) | dl;
        bb = d.z / NPB; dl = (uint32_t)(d.z - bb * NPB);
        pos = atomicAdd(&cw[w][bb], 1u); stage[pos] = ((uint32_t)s.z << 9) | dl;
        bb = d.w / NPB; dl = (uint32_t)(d.w - bb * NPB);
        pos = atomicAdd(&cw[w][bb], 1u); stage[pos] = ((uint32_t)s.w << 9) | dl;
    }
    __syncthreads();
    // coalesced write via binary search over loc
    for (int i = t; i < CEDGE; i += 512) {
        int lo = 0, hi = NBKT;
        while (hi - lo > 1) { int mid = (lo + hi) >> 1; if (loc[mid] <= (uint32_t)i) lo = mid; else hi = mid; }
        csr[segoff[lo] + (uint32_t)i] = stage[i];
    }
}

// ---------- mega: sort-own-bucket prologue + 20 fence-free iterations ----------
__global__ void __launch_bounds__(1024) mega_kernel(uint32_t* __restrict__ csr,
                                                    const uint32_t* __restrict__ bucket_base,
                                                    uint32_t* __restrict__ gPkA,
                                                    uint32_t* __restrict__ gPkB,
                                                    const uint8_t* __restrict__ nextT,
                                                    float* __restrict__ out,
                                                    uint32_t* __restrict__ bar) {
    __shared__ __align__(16) uint8_t shraw[55296];   // union: {st+binh} / {sPk+mask+packOwn}
    __shared__ uint8_t nT[NCHARS];
    __shared__ uint8_t sown[NPB];
    int t = threadIdx.x;
    int b = blockIdx.x;
    uint32_t base = bucket_base[b];
    uint32_t end  = bucket_base[b + 1];

    if (t < 512) ((uint32_t*)nT)[t] = ((const uint32_t*)nextT)[t];   // 2048 B
    const int line = b % 25;

    // --- prologue: bin-sort own bucket's two halves by src>>8 (block-local) ---
    {
        uint32_t* st   = (uint32_t*)shraw;              // 13312 words
        uint32_t* binh = (uint32_t*)(shraw + 53248);    // 512 words
        uint32_t n  = end - base;
        uint32_t n1 = (n + 1) >> 1;
        for (int h = 0; h < 2; ++h) {
            uint32_t r0  = h ? base + n1 : base;
            uint32_t cnt = h ? n - n1 : n1;
            if (cnt <= (uint32_t)HCAP) {                // block-uniform
                for (uint32_t i = t; i < cnt; i += 1024) st[i] = csr[r0 + i];
                if (t < 512) binh[t] = 0;
                __syncthreads();
                for (uint32_t i = t; i < cnt; i += 1024) atomicAdd(&binh[st[i] >> 17], 1u);
                __syncthreads();
                uint32_t v = (t < 512) ? binh[t] : 0u;
                __syncthreads();
                for (int off = 1; off < 512; off <<= 1) {
                    uint32_t x = (t < 512 && t >= off) ? binh[t - off] : 0u;
                    __syncthreads();
                    if (t < 512) binh[t] += x;
                    __syncthreads();
                }
                uint32_t excl = (t < 512) ? binh[t] - v : 0u;
                __syncthreads();
                if (t < 512) binh[t] = excl;
                __syncthreads();
                for (uint32_t i = t; i < cnt; i += 1024) {
                    uint32_t wv = st[i];
                    uint32_t pos = atomicAdd(&binh[wv >> 17], 1u);
                    csr[r0 + pos] = wv;
                }
            }
            __syncthreads();
        }
    }

    uint32_t* sPk     = (uint32_t*)shraw;               // 50000 B
    uint32_t* mask    = (uint32_t*)(shraw + 50000);     // 1600 B
    uint32_t* packOwn = (uint32_t*)(shraw + 51600);     // 200 B

    for (int p = 0; p < ITERS; ++p) {
        const uint32_t* curG = (p & 1) ? gPkB : gPkA;
        uint32_t*       nxtG = (p & 1) ? gPkA : gPkB;
        // coherent x4 reload of full packed state (bypasses stale L1/L2)
        {
            const u32x4* g4 = (const u32x4*)curG;
            int i0 = t, i1 = t + 1024, i2 = t + 2048;
            int i3 = t + 3072; if (i3 > X4N - 1) i3 = X4N - 1;
            const u32x4 *p0 = g4 + i0, *p1 = g4 + i1, *p2 = g4 + i2, *p3 = g4 + i3;
            u32x4 a0, a1, a2, a3;
            asm volatile(
                "global_load_dwordx4 %0, %4, off sc1\n\t"
                "global_load_dwordx4 %1, %5, off sc1\n\t"
                "global_load_dwordx4 %2, %6, off sc1\n\t"
                "global_load_dwordx4 %3, %7, off sc1\n\t"
                "s_waitcnt vmcnt(0)"
                : "=&v"(a0), "=&v"(a1), "=&v"(a2), "=&v"(a3)
                : "v"(p0), "v"(p1), "v"(p2), "v"(p3)
                : "memory");
            u32x4* s4 = (u32x4*)sPk;
            s4[i0] = a0; s4[i1] = a1; s4[i2] = a2; s4[i3] = a3;
        }
        if (t < NPB) mask[t] = 0;
        if (t < NPB / 8) packOwn[t] = 0;
        __syncthreads();

        // gather: edges from global (L2-local, src-sorted), state from LDS
        uint32_t e = base + t;
        for (; e + 3072 < end; e += 4096) {
            uint32_t w0 = csr[e], w1 = csr[e + 1024], w2 = csr[e + 2048], w3 = csr[e + 3072];
            uint32_t s0_ = w0 >> 9, s1_ = w1 >> 9, s2_ = w2 >> 9, s3_ = w3 >> 9;
            uint32_t n0 = (sPk[s0_ >> 3] >> ((s0_ & 7) << 2)) & 7u;
            uint32_t n1 = (sPk[s1_ >> 3] >> ((s1_ & 7) << 2)) & 7u;
            uint32_t n2 = (sPk[s2_ >> 3] >> ((s2_ & 7) << 2)) & 7u;
            uint32_t n3 = (sPk[s3_ >> 3] >> ((s3_ & 7) << 2)) & 7u;
            atomicOr(&mask[w0 & 511u], 1u << n0);
            atomicOr(&mask[w1 & 511u], 1u << n1);
            atomicOr(&mask[w2 & 511u], 1u << n2);
            atomicOr(&mask[w3 & 511u], 1u << n3);
        }
        for (; e < end; e += 1024) {
            uint32_t wv = csr[e];
            uint32_t s_ = wv >> 9;
            uint32_t nb = (sPk[s_ >> 3] >> ((s_ & 7) << 2)) & 7u;
            atomicOr(&mask[wv & 511u], 1u << nb);
        }
        __syncthreads();

        // own-node update + nibble pack
        if (t < NPB) {
            int node = b * NPB + t;
            uint32_t sOwn = (sPk[node >> 3] >> ((node & 7) << 2)) & 7u;
            uint8_t ns = nT[(mask[t] << 3) + sOwn];
            sown[t] = ns;
            atomicOr(&packOwn[t >> 3], (uint32_t)ns << ((t & 7) << 2));
        }
        __syncthreads();
        if (p < ITERS - 1) {
            if (t < NPB / 8)
                __hip_atomic_store(&nxtG[(NPB / 8) * b + t], packOwn[t],
                                   __ATOMIC_RELAXED, __HIP_MEMORY_SCOPE_AGENT);
            grid_barrier(bar, line, (uint32_t)(p + 1), 10u, 25u,
                         1664, MEG_TOP, 2112);
        }
    }
    __syncthreads();
    // one-hot output: 400 nodes * 8 floats, coalesced
    for (int f = t; f < NPB * 8; f += 1024) {
        int node = f >> 3;
        out[(size_t)b * (NPB * 8) + f] = ((f & 7) == (int)sown[node]) ? 1.f : 0.f;
    }
}

// ---------- fallback (tiny ws): R1 mask/atomicOr path ----------
__global__ void fb_decode(const float* __restrict__ s0, const float* __restrict__ T,
                          uint8_t* __restrict__ state, uint8_t* __restrict__ nextT,
                          uint32_t* __restrict__ mask) {
    int i = blockIdx.x * blockDim.x + threadIdx.x;
    if (i < NCHARS) {
        const float* row = T + i * 8;
        int t = 0;
        #pragma unroll
        for (int k = 1; k < 8; ++k) if (row[k] > 0.5f) t = k;
        nextT[i] = (uint8_t)t;
    }
    if (i < NN) {
        const float* row = s0 + i * 8;
        int s = 0;
        #pragma unroll
        for (int k = 1; k < 8; ++k) if (row[k] > 0.5f) s = k;
        state[i] = (uint8_t)s;
        mask[i] = 0u;
    }
}
__global__ void fb_edge(const int* __restrict__ src, const int* __restrict__ dst,
                        const uint8_t* __restrict__ state, uint32_t* __restrict__ mask) {
    int i = blockIdx.x * blockDim.x + threadIdx.x;
    int stride = gridDim.x * blockDim.x;
    for (int e = i; e < EE; e += stride) atomicOr(&mask[dst[e]], 1u << state[src[e]]);
}
__global__ void fb_update(uint8_t* __restrict__ state, uint32_t* __restrict__ mask,
                          const uint8_t* __restrict__ nextT) {
    int i = blockIdx.x * blockDim.x + threadIdx.x;
    if (i < NN) {
        uint32_t m = mask[i];
        state[i] = nextT[(m << 3) + state[i]];
        mask[i] = 0u;
    }
}
__global__ void fb_output(const uint8_t* __restrict__ state, float* __restrict__ out) {
    int i = blockIdx.x * blockDim.x + threadIdx.x;
    if (i < NN) {
        int s = state[i];
        float4 lo = make_float4(s == 0 ? 1.f : 0.f, s == 1 ? 1.f : 0.f,
                                s == 2 ? 1.f : 0.f, s == 3 ? 1.f : 0.f);
        float4 hi = make_float4(s == 4 ? 1.f : 0.f, s == 5 ? 1.f : 0.f,
                                s == 6 ? 1.f : 0.f, s == 7 ? 1.f : 0.f);
        float4* o = (float4*)(out + (size_t)i * 8);
        o[0] = lo;
        o[1] = hi;
    }
}

extern "C" void kernel_launch(void* const* d_in, const int* in_sizes, int n_in,
                              void* d_out, int out_size, void* d_ws, size_t ws_size,
                              hipStream_t stream) {
    const float* s0  = (const float*)d_in[0];
    const int*   ei  = (const int*)d_in[1];   // [2,E]: row0=src, row1=dst
    const float* T   = (const float*)d_in[2];
    float*       out = (float*)d_out;
    const int* src = ei;
    const int* dst = ei + EE;

    uint8_t* basep = (uint8_t*)d_ws;
    size_t off = 0;
    auto alloc = [&](size_t sz) -> void* {
        void* p = basep + off;
        off += (sz + 255) & ~(size_t)255;
        return p;
    };
    uint32_t* csr         = (uint32_t*)alloc(sizeof(uint32_t) * EE);
    uint32_t* bucket_base = (uint32_t*)alloc(sizeof(uint32_t) * (NBKT + 1));
    uint8_t*  nextT       = (uint8_t*)alloc(NCHARS);
    uint32_t* gPkA        = (uint32_t*)alloc(sizeof(uint32_t) * WPS);
    uint32_t* gPkB        = (uint32_t*)alloc(sizeof(uint32_t) * WPS);
    uint32_t* bar         = (uint32_t*)alloc(sizeof(uint32_t) * BAR_WORDS);
    bool have_ws = (off <= ws_size);

    if (have_ws) {
        hipMemsetAsync(bar, 0, sizeof(uint32_t) * BAR_WORDS, stream);
        decode_kernel<<<51, 256, 0, stream>>>(s0, T, gPkA, nextT);
        build_kernel<<<NCHUNK, 512, 0, stream>>>(src, dst, bucket_base, csr, bar);
        mega_kernel<<<NBKT, 1024, 0, stream>>>(csr, bucket_base, gPkA, gPkB,
                                               nextT, out, bar);
    } else {
        uint32_t* mask = (uint32_t*)d_ws;           // < 1 MB path
        uint8_t*  nT   = (uint8_t*)d_ws + 400128;
        uint8_t*  st   = (uint8_t*)d_ws + 402432;
        fb_decode<<<391, 256, 0, stream>>>(s0, T, st, nT, mask);
        for (int it = 0; it < ITERS; ++it) {
            fb_edge<<<2048, 256, 0, stream>>>(src, dst, st, mask);
            fb_update<<<391, 256, 0, stream>>>(st, mask, nT);
        }
        fb_output<<<391, 256, 0, stream>>>(st, out);
    }
}

// Round 13
// 271.057 us; speedup vs baseline: 1.0942x; 1.0942x over previous
//
#include <hip/hip_runtime.h>
#include <hip/hip_bf16.h>
#include <stdint.h>

// NeuralFSM as integer FSM (exact). R13:
//  - Fixed-capacity bucket regions (CAPB words each): bucket base = b*CAPB.
//    Build needs NO global scan and NO grid barriers; blocks reserve slices
//    via one atomicAdd per (block,bucket); final cursor value = bucket count.
//  - Build's write phase uses an LDS lookup table (slot -> bucket) instead of
//    R11/R12's 9-step binary search per edge.
//  - decode folded into build (striped over its 500 blocks).
//  - p4 src-sort back as a separate 500-block kernel (R12 showed merging it
//    into mega's prologue costs +38us vs p4's 500-wide parallelism).
//  - mega: R11's proven iteration loop verbatim (coherent x4 state reload,
//    fence-free 2-level grid barrier), base=b*CAPB, n=cursor[b].
//  - Dispatches: memsetAsync(bar) + build + p4 + mega.

#define NN 100000
#define EE 6400000
#define NCHARS 2048
#define ITERS 20

#define NBKT 250          // dst buckets == mega blocks
#define NPB 400           // nodes per bucket
#define WPS 12500         // words of packed state (NN/8)
#define X4N 3125          // WPS/4
#define CEDGE 12800       // edges per build block
#define NCHUNK 500        // build blocks
#define CAPB 27648        // fixed region capacity per bucket (mean 25600, +12.8 sigma)
#define HCAP 13824        // p4 half-bucket LDS cap

// ---- bar region (words; lines 64B apart); zeroed by hipMemsetAsync ----
#define MEG_TOP     2080
#define CUR_OFF     3328                // cursor/count[250]
#define BAR_WORDS   4096                // 16 KB

typedef uint32_t u32x4 __attribute__((ext_vector_type(4)));

__device__ inline void mega_barrier(uint32_t* bar, int line, uint32_t epoch) {
    __syncthreads();                      // drains vmcnt: prior ops at coherence pt
    if (threadIdx.x == 0) {
        uint32_t old = atomicAdd(&bar[1664 + line * 16], 1u);
        if (old + 1u == 10u * epoch) {
            uint32_t told = atomicAdd(&bar[MEG_TOP], 1u);
            if (told + 1u == 25u * epoch) {
                for (int r = 0; r < 25; ++r)
                    atomicExch(&bar[2112 + r * 16], epoch);
            }
        }
        while (__hip_atomic_load(&bar[2112 + line * 16], __ATOMIC_RELAXED,
                                 __HIP_MEMORY_SCOPE_AGENT) < epoch)
            __builtin_amdgcn_s_sleep(16);
    }
    __syncthreads();
}

// ---------- build: decode-stripe + count + reserve + scatter + lut write ----------
__global__ void __launch_bounds__(512) build_kernel(const int* __restrict__ src,
                                                    const int* __restrict__ dst,
                                                    const float* __restrict__ s0,
                                                    const float* __restrict__ T,
                                                    uint32_t* __restrict__ gPk0,
                                                    uint8_t* __restrict__ nextT,
                                                    uint32_t* __restrict__ csr,
                                                    uint32_t* __restrict__ bar) {
    __shared__ uint32_t stage[CEDGE];       // 51.2 KB
    __shared__ uint32_t cw[8][256];         // 8 KB: per-wave counts -> cursors
    __shared__ uint32_t scanb[512];
    __shared__ uint32_t loc[NBKT + 1];
    __shared__ uint32_t segoff[NBKT];
    __shared__ uint8_t  lut[CEDGE];         // 12.8 KB slot->bucket
    int t = threadIdx.x, w = t >> 6;
    int c = blockIdx.x;
    int e0 = c * CEDGE;
    const int4* ps4 = (const int4*)(src + e0);
    const int4* pd4 = (const int4*)(dst + e0);
    uint32_t* cursorG = bar + CUR_OFF;

    // --- decode stripe: block c packs nodes [c*200, c*200+200) -> 25 words ---
    if (t < 25) loc[t] = 0;
    __syncthreads();
    if (t < 200) {
        const float* row = s0 + ((size_t)c * 200 + t) * 8;
        int s = 0;
        #pragma unroll
        for (int q = 1; q < 8; ++q) if (row[q] > 0.5f) s = q;
        atomicOr(&loc[t >> 3], (uint32_t)s << ((t & 7) << 2));
    }
    __syncthreads();
    if (t < 25) gPk0[c * 25 + t] = loc[t];
    if (c < 4) {                             // nextT: 4 blocks x 512 entries
        const float* row = T + (c * 512 + t) * 8;
        int s = 0;
        #pragma unroll
        for (int q = 1; q < 8; ++q) if (row[q] > 0.5f) s = q;
        nextT[c * 512 + t] = (uint8_t)s;
    }
    __syncthreads();

    // --- count (int4 groups; edge group 4i..4i+3 -> wave (i%512)>>6) ---
    for (int i = t; i < 8 * 256; i += 512) ((uint32_t*)cw)[i] = 0;
    __syncthreads();
    for (int i = t; i < CEDGE / 4; i += 512) {
        int4 d = pd4[i];
        atomicAdd(&cw[w][d.x / NPB], 1u);
        atomicAdd(&cw[w][d.y / NPB], 1u);
        atomicAdd(&cw[w][d.z / NPB], 1u);
        atomicAdd(&cw[w][d.w / NPB], 1u);
    }
    __syncthreads();
    uint32_t tot = 0;
    if (t < NBKT) {
        #pragma unroll
        for (int w2 = 0; w2 < 8; ++w2) tot += cw[w2][t];
    }
    scanb[t] = tot;
    __syncthreads();
    for (int off = 1; off < 512; off <<= 1) {
        uint32_t x = (t >= off) ? scanb[t - off] : 0u;
        __syncthreads();
        scanb[t] += x;
        __syncthreads();
    }
    if (t < NBKT) {
        uint32_t excl = scanb[t] - tot;
        loc[t] = excl;
        uint32_t myStart = atomicAdd(&cursorG[t], tot);   // reserve slice
        segoff[t] = (uint32_t)t * CAPB + myStart - excl;
        uint32_t acc = excl;                 // counts -> per-wave stage cursors
        #pragma unroll
        for (int w2 = 0; w2 < 8; ++w2) {
            uint32_t cv = cw[w2][t];
            cw[w2][t] = acc;
            acc += cv;
        }
    }
    if (t == 0) loc[NBKT] = CEDGE;
    __syncthreads();
    // lut fill: thread b writes its own disjoint range
    for (int b = t; b < NBKT; b += 512) {
        uint32_t lo = loc[b], hi = loc[b + 1];
        for (uint32_t i = lo; i < hi; ++i) lut[i] = (uint8_t)b;
    }
    // scatter (IDENTICAL int4-group wave mapping as count phase)
    for (int i = t; i < CEDGE / 4; i += 512) {
        int4 d = pd4[i];
        int4 s = ps4[i];
        int bb; uint32_t dl, pos;
        bb = d.x / NPB; dl = (uint32_t)(d.x - bb * NPB);
        pos = atomicAdd(&cw[w][bb], 1u); stage[pos] = ((uint32_t)s.x << 9) | dl;
        bb = d.y / NPB; dl = (uint32_t)(d.y - bb * NPB);
        pos = atomicAdd(&cw[w][bb], 1u); stage[pos] = ((uint32_t)s.y << 9) | dl;
        bb = d.z / NPB; dl = (uint32_t)(d.z - bb * NPB);
        pos = atomicAdd(&cw[w][bb], 1u); stage[pos] = ((uint32_t)s.z << 9) | dl;
        bb = d.w / NPB; dl = (uint32_t)(d.w - bb * NPB);
        pos = atomicAdd(&cw[w][bb], 1u); stage[pos] = ((uint32_t)s.w << 9) | dl;
    }
    __syncthreads();
    // coalesced write via lut (2 LDS reads instead of 9-step binary search)
    for (int i = t; i < CEDGE; i += 512) {
        csr[segoff[lut[i]] + (uint32_t)i] = stage[i];
    }
}

// ---------- P4: bin-sort each half-bucket by src>>8 (gather locality) ----------
__global__ void __launch_bounds__(512) p4_sortsrc(uint32_t* __restrict__ csr,
                                                  const uint32_t* __restrict__ cntG) {
    __shared__ uint32_t st[HCAP];           // 55.3 KB
    __shared__ uint32_t binh[512];
    int t = threadIdx.x;
    int j = blockIdx.x;
    int b = j >> 1, h = j & 1;
    uint32_t n  = cntG[b];
    uint32_t n1 = (n + 1) >> 1;
    uint32_t r0 = (uint32_t)b * CAPB + (h ? n1 : 0);
    uint32_t cnt = h ? n - n1 : n1;
    if (cnt > HCAP) return;                 // leave unsorted (still correct)
    for (uint32_t i = t; i < cnt; i += 512) st[i] = csr[r0 + i];
    binh[t] = 0;
    __syncthreads();
    for (uint32_t i = t; i < cnt; i += 512) atomicAdd(&binh[st[i] >> 17], 1u);  // src>>8
    __syncthreads();
    uint32_t v = binh[t];
    __syncthreads();
    for (int off = 1; off < 512; off <<= 1) {
        uint32_t x = (t >= off) ? binh[t - off] : 0u;
        __syncthreads();
        binh[t] += x;
        __syncthreads();
    }
    uint32_t excl = binh[t] - v;
    __syncthreads();
    binh[t] = excl;                          // becomes cursor
    __syncthreads();
    for (uint32_t i = t; i < cnt; i += 512) {
        uint32_t w = st[i];
        uint32_t pos = atomicAdd(&binh[w >> 17], 1u);
        csr[r0 + pos] = w;
    }
}

// ---------- mega: fence-free persistent 20 iterations (R11 verbatim) ----------
__global__ void __launch_bounds__(1024) mega_kernel(const uint32_t* __restrict__ csr,
                                                    uint32_t* __restrict__ gPkA,
                                                    uint32_t* __restrict__ gPkB,
                                                    const uint8_t* __restrict__ nextT,
                                                    float* __restrict__ out,
                                                    uint32_t* __restrict__ bar) {
    __shared__ uint32_t sPk[WPS];           // 50 KB packed state
    __shared__ uint32_t mask[NPB];          // 1.6 KB
    __shared__ uint32_t packOwn[NPB / 8];
    __shared__ uint8_t  nT[NCHARS];
    __shared__ uint8_t  sown[NPB];
    int t = threadIdx.x;
    int b = blockIdx.x;
    uint32_t base = (uint32_t)b * CAPB;
    uint32_t end  = base + bar[CUR_OFF + b];     // bucket count (kernel-boundary coherent)

    if (t < 512) ((uint32_t*)nT)[t] = ((const uint32_t*)nextT)[t];   // 2048 B
    const int line = b % 25;

    for (int p = 0; p < ITERS; ++p) {
        const uint32_t* curG = (p & 1) ? gPkB : gPkA;
        uint32_t*       nxtG = (p & 1) ? gPkA : gPkB;
        // coherent x4 reload of full packed state (bypasses stale L1/L2)
        {
            const u32x4* g4 = (const u32x4*)curG;
            int i0 = t, i1 = t + 1024, i2 = t + 2048;
            int i3 = t + 3072; if (i3 > X4N - 1) i3 = X4N - 1;
            const u32x4 *p0 = g4 + i0, *p1 = g4 + i1, *p2 = g4 + i2, *p3 = g4 + i3;
            u32x4 a0, a1, a2, a3;
            asm volatile(
                "global_load_dwordx4 %0, %4, off sc1\n\t"
                "global_load_dwordx4 %1, %5, off sc1\n\t"
                "global_load_dwordx4 %2, %6, off sc1\n\t"
                "global_load_dwordx4 %3, %7, off sc1\n\t"
                "s_waitcnt vmcnt(0)"
                : "=&v"(a0), "=&v"(a1), "=&v"(a2), "=&v"(a3)
                : "v"(p0), "v"(p1), "v"(p2), "v"(p3)
                : "memory");
            u32x4* s4 = (u32x4*)sPk;
            s4[i0] = a0; s4[i1] = a1; s4[i2] = a2; s4[i3] = a3;
        }
        if (t < NPB) mask[t] = 0;
        if (t < NPB / 8) packOwn[t] = 0;
        __syncthreads();

        // gather: edges from global (L2-resident, src-sorted), state from LDS
        uint32_t e = base + t;
        for (; e + 3072 < end; e += 4096) {
            uint32_t w0 = csr[e], w1 = csr[e + 1024], w2 = csr[e + 2048], w3 = csr[e + 3072];
            uint32_t s0_ = w0 >> 9, s1_ = w1 >> 9, s2_ = w2 >> 9, s3_ = w3 >> 9;
            uint32_t n0 = (sPk[s0_ >> 3] >> ((s0_ & 7) << 2)) & 7u;
            uint32_t n1 = (sPk[s1_ >> 3] >> ((s1_ & 7) << 2)) & 7u;
            uint32_t n2 = (sPk[s2_ >> 3] >> ((s2_ & 7) << 2)) & 7u;
            uint32_t n3 = (sPk[s3_ >> 3] >> ((s3_ & 7) << 2)) & 7u;
            atomicOr(&mask[w0 & 511u], 1u << n0);
            atomicOr(&mask[w1 & 511u], 1u << n1);
            atomicOr(&mask[w2 & 511u], 1u << n2);
            atomicOr(&mask[w3 & 511u], 1u << n3);
        }
        for (; e < end; e += 1024) {
            uint32_t wv = csr[e];
            uint32_t s_ = wv >> 9;
            uint32_t nb = (sPk[s_ >> 3] >> ((s_ & 7) << 2)) & 7u;
            atomicOr(&mask[wv & 511u], 1u << nb);
        }
        __syncthreads();

        // own-node update + nibble pack
        if (t < NPB) {
            int node = b * NPB + t;
            uint32_t sOwn = (sPk[node >> 3] >> ((node & 7) << 2)) & 7u;
            uint8_t ns = nT[(mask[t] << 3) + sOwn];
            sown[t] = ns;
            atomicOr(&packOwn[t >> 3], (uint32_t)ns << ((t & 7) << 2));
        }
        __syncthreads();
        if (p < ITERS - 1) {
            if (t < NPB / 8)
                __hip_atomic_store(&nxtG[(NPB / 8) * b + t], packOwn[t],
                                   __ATOMIC_RELAXED, __HIP_MEMORY_SCOPE_AGENT);
            mega_barrier(bar, line, (uint32_t)(p + 1));
        }
    }
    __syncthreads();
    // one-hot output: 400 nodes * 8 floats, coalesced
    for (int f = t; f < NPB * 8; f += 1024) {
        int node = f >> 3;
        out[(size_t)b * (NPB * 8) + f] = ((f & 7) == (int)sown[node]) ? 1.f : 0.f;
    }
}

// ---------- fallback (tiny ws): R1 mask/atomicOr path ----------
__global__ void fb_decode(const float* __restrict__ s0, const float* __restrict__ T,
                          uint8_t* __restrict__ state, uint8_t* __restrict__ nextT,
                          uint32_t* __restrict__ mask) {
    int i = blockIdx.x * blockDim.x + threadIdx.x;
    if (i < NCHARS) {
        const float* row = T + i * 8;
        int t = 0;
        #pragma unroll
        for (int k = 1; k < 8; ++k) if (row[k] > 0.5f) t = k;
        nextT[i] = (uint8_t)t;
    }
    if (i < NN) {
        const float* row = s0 + i * 8;
        int s = 0;
        #pragma unroll
        for (int k = 1; k < 8; ++k) if (row[k] > 0.5f) s = k;
        state[i] = (uint8_t)s;
        mask[i] = 0u;
    }
}
__global__ void fb_edge(const int* __restrict__ src, const int* __restrict__ dst,
                        const uint8_t* __restrict__ state, uint32_t* __restrict__ mask) {
    int i = blockIdx.x * blockDim.x + threadIdx.x;
    int stride = gridDim.x * blockDim.x;
    for (int e = i; e < EE; e += stride) atomicOr(&mask[dst[e]], 1u << state[src[e]]);
}
__global__ void fb_update(uint8_t* __restrict__ state, uint32_t* __restrict__ mask,
                          const uint8_t* __restrict__ nextT) {
    int i = blockIdx.x * blockDim.x + threadIdx.x;
    if (i < NN) {
        uint32_t m = mask[i];
        state[i] = nextT[(m << 3) + state[i]];
        mask[i] = 0u;
    }
}
__global__ void fb_output(const uint8_t* __restrict__ state, float* __restrict__ out) {
    int i = blockIdx.x * blockDim.x + threadIdx.x;
    if (i < NN) {
        int s = state[i];
        float4 lo = make_float4(s == 0 ? 1.f : 0.f, s == 1 ? 1.f : 0.f,
                                s == 2 ? 1.f : 0.f, s == 3 ? 1.f : 0.f);
        float4 hi = make_float4(s == 4 ? 1.f : 0.f, s == 5 ? 1.f : 0.f,
                                s == 6 ? 1.f : 0.f, s == 7 ? 1.f : 0.f);
        float4* o = (float4*)(out + (size_t)i * 8);
        o[0] = lo;
        o[1] = hi;
    }
}

extern "C" void kernel_launch(void* const* d_in, const int* in_sizes, int n_in,
                              void* d_out, int out_size, void* d_ws, size_t ws_size,
                              hipStream_t stream) {
    const float* s0  = (const float*)d_in[0];
    const int*   ei  = (const int*)d_in[1];   // [2,E]: row0=src, row1=dst
    const float* T   = (const float*)d_in[2];
    float*       out = (float*)d_out;
    const int* src = ei;
    const int* dst = ei + EE;

    uint8_t* basep = (uint8_t*)d_ws;
    size_t off = 0;
    auto alloc = [&](size_t sz) -> void* {
        void* p = basep + off;
        off += (sz + 255) & ~(size_t)255;
        return p;
    };
    uint32_t* csr   = (uint32_t*)alloc(sizeof(uint32_t) * (size_t)NBKT * CAPB);
    uint8_t*  nextT = (uint8_t*)alloc(NCHARS);
    uint32_t* gPkA  = (uint32_t*)alloc(sizeof(uint32_t) * WPS);
    uint32_t* gPkB  = (uint32_t*)alloc(sizeof(uint32_t) * WPS);
    uint32_t* bar   = (uint32_t*)alloc(sizeof(uint32_t) * BAR_WORDS);
    bool have_ws = (off <= ws_size);

    if (have_ws) {
        hipMemsetAsync(bar, 0, sizeof(uint32_t) * BAR_WORDS, stream);
        build_kernel<<<NCHUNK, 512, 0, stream>>>(src, dst, s0, T, gPkA, nextT, csr, bar);
        p4_sortsrc<<<NBKT * 2, 512, 0, stream>>>(csr, bar + CUR_OFF);
        mega_kernel<<<NBKT, 1024, 0, stream>>>(csr, gPkA, gPkB, nextT, out, bar);
    } else {
        uint32_t* mask = (uint32_t*)d_ws;           // < 1 MB path
        uint8_t*  nT   = (uint8_t*)d_ws + 400128;
        uint8_t*  st   = (uint8_t*)d_ws + 402432;
        fb_decode<<<391, 256, 0, stream>>>(s0, T, st, nT, mask);
        for (int it = 0; it < ITERS; ++it) {
            fb_edge<<<2048, 256, 0, stream>>>(src, dst, st, mask);
            fb_update<<<391, 256, 0, stream>>>(st, mask, nT);
        }
        fb_output<<<391, 256, 0, stream>>>(st, out);
    }
}